// Round 1
// 311.868 us; speedup vs baseline: 1.1530x; 1.1530x over previous
//
#include <hip/hip_runtime.h>
#include <cstdint>

// LSTM cell: B=8192, DIM_IN=1024, DIM_OUT=1024, d=2048
// gates = [X|H][8192,2048] @ W[2048,4096] + b ; epilogue fused into GEMM.
// R2: 256x256 tile, BK=64, 8 waves, deep pipeline (counted vmcnt(4), raw
// s_barrier, no drain-to-0 in loop), XOR-swizzled LDS (chunk ^= (row>>1)&3,
// pre-swizzled global staging sources), setprio around MFMA clusters,
// bijective XCD block swizzle. W pre-permuted: n'' = (j>>4)*64 + g*16 + (j&15)
// so each wave's 64 n''-cols = 16 j-cols x 4 gates (in-register epilogue).

#define B_ROWS 8192
#define DK 2048
#define DOUT 1024
#define BM 256
#define BN 256
#define BK 64
#define NKT (DK / BK)   // 32 K-tiles

typedef __bf16 bf16x8 __attribute__((ext_vector_type(8)));
typedef __bf16 bf16x4 __attribute__((ext_vector_type(4)));
typedef float f32x4 __attribute__((ext_vector_type(4)));

__device__ inline void load16_to_lds(const __bf16* gsrc, __bf16* ldst) {
    __builtin_amdgcn_global_load_lds(
        (const __attribute__((address_space(1))) void*)gsrc,
        (__attribute__((address_space(3))) void*)ldst,
        16, 0, 0);
}

// sigmoid(x) = 1/(1+2^(-x*log2e)); tanh(x) = 1 - 2/(1+2^(2x*log2e))
__device__ inline float fast_sigmoid(float x) {
    return __builtin_amdgcn_rcpf(1.0f + __builtin_amdgcn_exp2f(-1.442695041f * x));
}
__device__ inline float fast_tanh(float x) {
    return 1.0f - 2.0f * __builtin_amdgcn_rcpf(1.0f + __builtin_amdgcn_exp2f(2.885390082f * x));
}

// ---- prep 1: X = bf16(concat(x,h))  [8192][2048] row-major ----
__global__ __launch_bounds__(256) void prep_x(const float* __restrict__ x,
                                              const float* __restrict__ h,
                                              __bf16* __restrict__ X) {
    int id = blockIdx.x * 256 + threadIdx.x;
    int b = id >> 9;
    int k = (id & 511) * 4;
    float4 v;
    if (k < 1024) v = *(const float4*)&x[(size_t)b * 1024 + k];
    else          v = *(const float4*)&h[(size_t)b * 1024 + (k - 1024)];
    bf16x4 o = { (__bf16)v.x, (__bf16)v.y, (__bf16)v.z, (__bf16)v.w };
    *(bf16x4*)&X[(size_t)b * 2048 + k] = o;
}

// ---- prep 2: Wt[n''][k] = bf16(W_g[k][j]); n'' = (j>>4)*64 + g*16 + (j&15)
__global__ __launch_bounds__(256) void prep_w(const float* __restrict__ WI,
                                              const float* __restrict__ WF,
                                              const float* __restrict__ WG,
                                              const float* __restrict__ WO,
                                              __bf16* __restrict__ Wt) {
    int kb = blockIdx.x;       // 0..63  (k tiles of 32)
    int jb = blockIdx.y;       // 0..31  (j tiles of 32)
    int j0 = jb * 32;
    __shared__ float t[32][33];
    int tx = threadIdx.x, ty = threadIdx.y;   // block (32,8)
    const float* Ws[4] = {WI, WF, WG, WO};
#pragma unroll
    for (int g = 0; g < 4; ++g) {
        const float* W = Ws[g];
#pragma unroll
        for (int yy = 0; yy < 32; yy += 8) {
            int k = kb * 32 + ty + yy;
            t[ty + yy][tx] = W[(size_t)k * 1024 + j0 + tx];
        }
        __syncthreads();
#pragma unroll
        for (int yy = 0; yy < 32; yy += 8) {
            int r = ty + yy;                  // 0..31: jlo = r&15, jhi-sub = r>>4
            int npp = (jb * 2 + (r >> 4)) * 64 + g * 16 + (r & 15);
            Wt[(size_t)npp * 2048 + kb * 32 + tx] = (__bf16)t[tx][r];
        }
        __syncthreads();
    }
}

// ---- fused GEMM + LSTM epilogue, 256^2 deep-pipelined ----
__global__ __launch_bounds__(512, 2) void lstm_gemm(
    const __bf16* __restrict__ Xbf, const __bf16* __restrict__ Wt,
    const float* __restrict__ c,
    const float* __restrict__ bI, const float* __restrict__ bF,
    const float* __restrict__ bG, const float* __restrict__ bO,
    float* __restrict__ outH, float* __restrict__ outC)
{
    // [dbuf][A=0/B=1][khalf][256 rows x 32 cols bf16] = 8 x 16KB = 128KB
    __shared__ __bf16 lds[2][2][2][8192];

    const int tid  = threadIdx.x;
    const int lane = tid & 63;
    const int wave = tid >> 6;
    const int wm = wave >> 2;          // 0..1 : 128-row half
    const int wn = wave & 3;           // 0..3 : 64-col (n'') slice

    // bijective XCD swizzle (512 % 8 == 0). XCD x gets ids x*64..x*64+63:
    // nb in {2x,2x+1} -> one B-panel resident per XCD round, A streams via L3.
    const int bid = blockIdx.x;
    const int id  = (bid & 7) * 64 + (bid >> 3);
    const int mb = id & 31;
    const int nb = id >> 5;
    const int m0 = mb * BM;
    const int n0 = nb * BN;

    // ---- staging sources: linear LDS dest, pre-swizzled global source ----
    // unit = [256][32] bf16 = 16KB; thread covers bytes o0 and o0+8192.
    // physical chunk pk at (row,pk) must hold logical chunk pk ^ ((row>>1)&3).
    const int o0  = wave * 1024 + lane * 16;       // byte offset in unit (q=0)
    const int r0  = o0 >> 6;                       // row (q=0); q=1 row = r0+128
    const int lc0 = ((o0 >> 4) & 3) ^ ((r0 >> 1) & 3);  // same for q=1 (row+128)
    const __bf16* gA0 = Xbf + (size_t)(m0 + r0)       * DK + lc0 * 8;
    const __bf16* gA1 = Xbf + (size_t)(m0 + r0 + 128) * DK + lc0 * 8;
    const __bf16* gB0 = Wt  + (size_t)(n0 + r0)       * DK + lc0 * 8;
    const __bf16* gB1 = Wt  + (size_t)(n0 + r0 + 128) * DK + lc0 * 8;
    const int ls0 = wave * 512;        // element offset in unit (1024B)
    const int ls1 = ls0 + 4096;        // +8192B

    // ---- swizzled ds_read lane addressing ----
    const int lr = lane & 15;
    const int pc = (lane >> 4) ^ ((lr >> 1) & 3);  // physical chunk
    const int ae = (wm * 128 + lr) * 32 + pc * 8;  // element offset, A tile
    const int be = (wn * 64  + lr) * 32 + pc * 8;  // element offset, B tile

    f32x4 acc[8][4];
#pragma unroll
    for (int i = 0; i < 8; ++i)
#pragma unroll
        for (int g = 0; g < 4; ++g) acc[i][g] = (f32x4){0.f, 0.f, 0.f, 0.f};

#define STAGE_A(d_, kh_, ko_) do { \
    load16_to_lds(gA0 + (ko_) + (kh_) * 32, &lds[d_][0][kh_][ls0]); \
    load16_to_lds(gA1 + (ko_) + (kh_) * 32, &lds[d_][0][kh_][ls1]); } while (0)
#define STAGE_B(d_, kh_, ko_) do { \
    load16_to_lds(gB0 + (ko_) + (kh_) * 32, &lds[d_][1][kh_][ls0]); \
    load16_to_lds(gB1 + (ko_) + (kh_) * 32, &lds[d_][1][kh_][ls1]); } while (0)

    // prologue: stage tile 0's 4 units in consumption order (8 loads)
    STAGE_A(0, 0, 0);
    STAGE_B(0, 0, 0);
    STAGE_A(0, 1, 0);
    STAGE_B(0, 1, 0);

    // Steady state: at each gp0 phase exactly 2 stage-units (4 loads) are
    // younger than the unit consumed -> vmcnt(4) guarantees it landed.
    // t=31 prefetch is masked to tile 0 (garbage, never read) to keep the
    // vmcnt algebra uniform.
#pragma unroll 2
    for (int t = 0; t < NKT; ++t) {
        const int d  = t & 1;
        const int dn = d ^ 1;
        const int ko = ((t + 1) & (NKT - 1)) * BK;
#pragma unroll
        for (int kh = 0; kh < 2; ++kh) {
            // ---- phase gp=0: gates 0,1 ----
            asm volatile("s_waitcnt vmcnt(4) lgkmcnt(0)" ::: "memory");
            __builtin_amdgcn_s_barrier();
            asm volatile("" ::: "memory");   // pin stages below the barrier
            bf16x8 a[8], b0, b1;
#pragma unroll
            for (int mi = 0; mi < 8; ++mi)
                a[mi] = *(const bf16x8*)&lds[d][0][kh][ae + mi * 512];
            b0 = *(const bf16x8*)&lds[d][1][kh][be];
            b1 = *(const bf16x8*)&lds[d][1][kh][be + 512];
            STAGE_A(dn, kh, ko);
            __builtin_amdgcn_s_setprio(1);
#pragma unroll
            for (int mi = 0; mi < 8; ++mi) {
                acc[mi][0] = __builtin_amdgcn_mfma_f32_16x16x32_bf16(a[mi], b0, acc[mi][0], 0, 0, 0);
                acc[mi][1] = __builtin_amdgcn_mfma_f32_16x16x32_bf16(a[mi], b1, acc[mi][1], 0, 0, 0);
            }
            __builtin_amdgcn_s_setprio(0);

            // ---- phase gp=1: gates 2,3 (A frags reused) ----
            asm volatile("s_waitcnt lgkmcnt(0)" ::: "memory");
            __builtin_amdgcn_s_barrier();
            asm volatile("" ::: "memory");
            bf16x8 b2 = *(const bf16x8*)&lds[d][1][kh][be + 1024];
            bf16x8 b3 = *(const bf16x8*)&lds[d][1][kh][be + 1536];
            STAGE_B(dn, kh, ko);
            __builtin_amdgcn_s_setprio(1);
#pragma unroll
            for (int mi = 0; mi < 8; ++mi) {
                acc[mi][2] = __builtin_amdgcn_mfma_f32_16x16x32_bf16(a[mi], b2, acc[mi][2], 0, 0, 0);
                acc[mi][3] = __builtin_amdgcn_mfma_f32_16x16x32_bf16(a[mi], b3, acc[mi][3], 0, 0, 0);
            }
            __builtin_amdgcn_s_setprio(0);
        }
    }
#undef STAGE_A
#undef STAGE_B

    // epilogue: C/D layout col=lane&15, row=(lane>>4)*4+reg; acc[mi][g] = gate g
    const int col = lane & 15;
    const int j = (nb * 4 + wn) * 16 + col;        // original gate column
    const float biI = bI[j], biF = bF[j], biG = bG[j], biO = bO[j];
    const int rbase = m0 + wm * 128 + ((lane >> 4) << 2);
#pragma unroll
    for (int mi = 0; mi < 8; ++mi) {
#pragma unroll
        for (int r = 0; r < 4; ++r) {
            int row = rbase + mi * 16 + r;
            float I = fast_sigmoid(acc[mi][0][r] + biI);
            float F = fast_sigmoid(acc[mi][1][r] + biF);
            float G = fast_tanh(acc[mi][2][r] + biG);
            float O = fast_sigmoid(acc[mi][3][r] + biO);
            size_t idx = (size_t)row * DOUT + j;
            float Cn = F * c[idx] + I * G;
            outH[idx] = O * fast_tanh(Cn);
            outC[idx] = Cn;
        }
    }
}

extern "C" void kernel_launch(void* const* d_in, const int* in_sizes, int n_in,
                              void* d_out, int out_size, void* d_ws, size_t ws_size,
                              hipStream_t stream) {
    const float* x  = (const float*)d_in[0];
    const float* h  = (const float*)d_in[1];
    const float* c  = (const float*)d_in[2];
    const float* WI = (const float*)d_in[3];
    const float* bI = (const float*)d_in[4];
    const float* WF = (const float*)d_in[5];
    const float* bF = (const float*)d_in[6];
    const float* WG = (const float*)d_in[7];
    const float* bG = (const float*)d_in[8];
    const float* WO = (const float*)d_in[9];
    const float* bO = (const float*)d_in[10];

    __bf16* Xbf = (__bf16*)d_ws;                                    // 32 MB
    __bf16* Wt  = (__bf16*)((char*)d_ws + (size_t)B_ROWS * DK * 2); // 16 MB
    float* outH = (float*)d_out;
    float* outC = outH + (size_t)B_ROWS * DOUT;

    prep_x<<<(B_ROWS * DK / 4) / 256, 256, 0, stream>>>(x, h, Xbf);
    prep_w<<<dim3(DK / 32, DOUT / 32), dim3(32, 8), 0, stream>>>(WI, WF, WG, WO, Wt);
    lstm_gemm<<<dim3((B_ROWS / BM) * (4 * DOUT / BN)), dim3(512), 0, stream>>>(
        Xbf, Wt, c, bI, bF, bG, bO, outH, outC);
}